// Round 20
// baseline (79.813 us; speedup 1.0000x reference)
//
#include <hip/hip_runtime.h>
#include <math.h>

#define H   128
#define NS  1024
#define NE  512
#define M   1024
#define K2  2.8853900817779268f   // 2*log2(e)

typedef float v4 __attribute__((ext_vector_type(4)));
typedef float v2 __attribute__((ext_vector_type(2)));

__device__ __forceinline__ float exp2_fast(float x) {
#if __has_builtin(__builtin_amdgcn_exp2f)
    return __builtin_amdgcn_exp2f(x);
#else
    return __expf(x * 0.6931471805599453f);
#endif
}

__device__ __forceinline__ float fast_tanh(float x) {
    float e = __expf(2.0f * x);
    float r = __builtin_amdgcn_rcpf(1.0f + e);
    return 1.0f - 2.0f * r;
}

// ---- transpose (+K2 scale) the weight matrices ---------------------------
__global__ __launch_bounds__(256) void k_tr(const float* __restrict__ Wc_s,
                                            const float* __restrict__ Wc_e,
                                            const float* __restrict__ W_lin,
                                            float* __restrict__ WT_s1, float* __restrict__ WT_s2,
                                            float* __restrict__ WT_e1, float* __restrict__ WT_e2,
                                            float* __restrict__ WT_lin) {
    int idx = blockIdx.x * 256 + threadIdx.x;
    if (idx < 65536) {
        int t = idx >> 14, r = idx & 16383, k = r >> 7, hh = r & 127;
        const float* src = (t < 2) ? Wc_s : Wc_e;
        int off = (t & 1) * H;
        float v = K2 * src[hh * 256 + off + k];
        float* dst = (t == 0) ? WT_s1 : (t == 1) ? WT_s2 : (t == 2) ? WT_e1 : WT_e2;
        dst[r] = v;
    } else {
        int j2 = idx - 65536;             // [0, 49152)
        int k = j2 >> 7, a = j2 & 127;
        WT_lin[j2] = W_lin[a * 384 + k];
    }
}

// ---- projections -> exp2 domain; 16 rows/block everywhere -----------------
// A-path (blocks 0..95): transposed output EAT[h][n]
// B-path (blocks 96..223): normal output EB[m][h]
__global__ __launch_bounds__(256) void k_proj(const float* __restrict__ stmts,
                                              const float* __restrict__ eres,
                                              const float* __restrict__ attender,
                                              const float* __restrict__ WT_s1,
                                              const float* __restrict__ WT_s2,
                                              const float* __restrict__ WT_e1,
                                              const float* __restrict__ WT_e2,
                                              const float* __restrict__ bc_s,
                                              const float* __restrict__ bc_e,
                                              float* __restrict__ EAT_s, float* __restrict__ EB_s,
                                              float* __restrict__ EAT_e, float* __restrict__ EB_e) {
    __shared__ float xr[16][H];
    __shared__ float red[16][H];
    int b   = blockIdx.x;
    int tid = threadIdx.x;
    int t    = tid & 127;
    int half = tid >> 7;

    const float *X, *WT, *bias; float* O; int r0, N; bool tr;
    if (b < 64)       { X = stmts;    WT = WT_s1; bias = bc_s;    O = EAT_s; r0 = b * 16;         N = NS; tr = true;  }
    else if (b < 96)  { X = eres;     WT = WT_e1; bias = bc_e;    O = EAT_e; r0 = (b - 64) * 16;  N = NE; tr = true;  }
    else if (b < 160) { X = attender; WT = WT_s2; bias = nullptr; O = EB_s;  r0 = (b - 96) * 16;  N = M;  tr = false; }
    else              { X = attender; WT = WT_e2; bias = nullptr; O = EB_e;  r0 = (b - 160) * 16; N = M;  tr = false; }

    for (int i = tid; i < 16 * H; i += 256) xr[i >> 7][i & 127] = X[(r0 + (i >> 7)) * H + (i & 127)];
    __syncthreads();
    float b0 = (bias && half == 0) ? K2 * bias[t] : 0.0f;
    float acc[16];
    #pragma unroll
    for (int r = 0; r < 16; ++r) acc[r] = b0;
    int k0 = half * 64;
    #pragma unroll 4
    for (int k = k0; k < k0 + 64; ++k) {
        float wv = WT[k * H + t];
        #pragma unroll
        for (int r = 0; r < 16; ++r) acc[r] += xr[r][k] * wv;
    }
    if (half) {
        #pragma unroll
        for (int r = 0; r < 16; ++r) red[r][t] = acc[r];
    }
    __syncthreads();
    if (tr) {
        if (!half) {
            #pragma unroll
            for (int r = 0; r < 16; ++r) xr[r][t] = exp2_fast(acc[r] + red[r][t]);
        }
        __syncthreads();
        int hh  = tid >> 1;
        int seg = (tid & 1) * 8;
        float4 v0 = make_float4(xr[seg + 0][hh], xr[seg + 1][hh], xr[seg + 2][hh], xr[seg + 3][hh]);
        float4 v1 = make_float4(xr[seg + 4][hh], xr[seg + 5][hh], xr[seg + 6][hh], xr[seg + 7][hh]);
        *(float4*)(O + (size_t)hh * N + r0 + seg)     = v0;
        *(float4*)(O + (size_t)hh * N + r0 + seg + 4) = v1;
    } else {
        if (!half) {
            #pragma unroll
            for (int r = 0; r < 16; ++r) O[(r0 + r) * H + t] = exp2_fast(acc[r] + red[r][t]);
        }
    }
}

// ---- fused score + softmax + context --------------------------------------
// score = -2 * sum_h ws[h]/(1+Ea*Eb)  (const dropped).  No max-subtraction.
// QUAD: one rcp per 4 h's.
#define QUAD(a0,a1,a2,a3, b0,b1,b2,b3, w0,w1,w2,w3, accv)              \
    { float q0 = fmaf(a0, b0, 1.0f), q1 = fmaf(a1, b1, 1.0f);          \
      float q2 = fmaf(a2, b2, 1.0f), q3 = fmaf(a3, b3, 1.0f);          \
      float d01 = q0 * q1, d23 = q2 * q3;                              \
      float n01 = w0 * q1; n01 = fmaf(w1, q0, n01);                    \
      float n23 = w2 * q3; n23 = fmaf(w3, q2, n23);                    \
      float nn = n01 * d23; nn = fmaf(n23, d01, nn);                   \
      float rr = __builtin_amdgcn_rcpf(d01 * d23);                     \
      accv = fmaf(nn, rr, accv); }

__global__ __launch_bounds__(512, 4) void k_score_ctx(const float* __restrict__ EAT_s,
                                                      const float* __restrict__ EB_s,
                                                      const float* __restrict__ ws_s,
                                                      const float* __restrict__ EAT_e,
                                                      const float* __restrict__ EB_e,
                                                      const float* __restrict__ ws_e,
                                                      const float* __restrict__ stmts,
                                                      const float* __restrict__ eres,
                                                      float* __restrict__ ctx_s,
                                                      float* __restrict__ ctx_e) {
    __shared__ float partial[16][257];  // h-half combine buffer
    __shared__ float wbuf[1024][4];     // w values (e-blocks: rows 0..511)
    __shared__ float part[4][4][H];     // ctx partials
    __shared__ float scrs[4][4], rzl[4];

    int b = blockIdx.x;                 // 0..511
    bool is_e = (b >= 256);
    int m0 = (is_e ? (b - 256) : b) * 4;
    const float* EAT = is_e ? EAT_e : EAT_s;
    const float* EB  = is_e ? EB_e  : EB_s;
    const float* wsv = is_e ? ws_e  : ws_s;
    const float* X   = is_e ? eres  : stmts;
    float* ctxout    = is_e ? ctx_e : ctx_s;
    int N  = is_e ? NE : NS;
    int NL = is_e ? 2 : 4;              // n's per thread
    int t  = threadIdx.x;
    int tq = t & 255;
    int hg = t >> 8;                    // 0/1: h-half
    int hbase = hg * 64;

    float acc[4][4] = {{0.f,0.f,0.f,0.f},{0.f,0.f,0.f,0.f},
                       {0.f,0.f,0.f,0.f},{0.f,0.f,0.f,0.f}};

    if (!is_e) {
        const float* base = EAT + 4 * tq;
        v4 a[4], an[4];
        #pragma unroll
        for (int k = 0; k < 4; ++k) a[k] = *(const v4*)(base + (size_t)(hbase + k) * NS);
        for (int ch = 0; ch < 16; ++ch) {
            int h0 = hbase + ch * 4;
            if (ch < 15) {
                #pragma unroll
                for (int k = 0; k < 4; ++k)
                    an[k] = *(const v4*)(base + (size_t)(h0 + 4 + k) * NS);
            }
            float wv[4];
            #pragma unroll
            for (int k = 0; k < 4; ++k) wv[k] = wsv[h0 + k];         // uniform
            #pragma unroll
            for (int mj = 0; mj < 4; ++mj) {
                float b0 = EB[(size_t)(m0 + mj) * H + h0 + 0];       // uniform
                float b1 = EB[(size_t)(m0 + mj) * H + h0 + 1];
                float b2 = EB[(size_t)(m0 + mj) * H + h0 + 2];
                float b3 = EB[(size_t)(m0 + mj) * H + h0 + 3];
                #pragma unroll
                for (int i = 0; i < 4; ++i)
                    QUAD(a[0][i], a[1][i], a[2][i], a[3][i],
                         b0, b1, b2, b3, wv[0], wv[1], wv[2], wv[3], acc[i][mj]);
            }
            #pragma unroll
            for (int k = 0; k < 4; ++k) a[k] = an[k];
        }
    } else {
        const float* base = EAT + 2 * tq;
        v2 a[4], an[4];
        #pragma unroll
        for (int k = 0; k < 4; ++k) a[k] = *(const v2*)(base + (size_t)(hbase + k) * NE);
        for (int ch = 0; ch < 16; ++ch) {
            int h0 = hbase + ch * 4;
            if (ch < 15) {
                #pragma unroll
                for (int k = 0; k < 4; ++k)
                    an[k] = *(const v2*)(base + (size_t)(h0 + 4 + k) * NE);
            }
            float wv[4];
            #pragma unroll
            for (int k = 0; k < 4; ++k) wv[k] = wsv[h0 + k];
            #pragma unroll
            for (int mj = 0; mj < 4; ++mj) {
                float b0 = EB[(size_t)(m0 + mj) * H + h0 + 0];
                float b1 = EB[(size_t)(m0 + mj) * H + h0 + 1];
                float b2 = EB[(size_t)(m0 + mj) * H + h0 + 2];
                float b3 = EB[(size_t)(m0 + mj) * H + h0 + 3];
                #pragma unroll
                for (int i = 0; i < 2; ++i)
                    QUAD(a[0][i], a[1][i], a[2][i], a[3][i],
                         b0, b1, b2, b3, wv[0], wv[1], wv[2], wv[3], acc[i][mj]);
            }
            #pragma unroll
            for (int k = 0; k < 4; ++k) a[k] = an[k];
        }
    }

    // ---- combine h-halves (hg1 -> LDS, hg0 adds), then exp + sum ----
    if (hg) {
        for (int i = 0; i < NL; ++i)
            #pragma unroll
            for (int j = 0; j < 4; ++j) partial[i * 4 + j][tq] = acc[i][j];
    }
    __syncthreads();
    int wave = t >> 6;                  // hg0 threads: waves 0..3
    if (!hg) {
        float w[4][4], sm[4];
        #pragma unroll
        for (int j = 0; j < 4; ++j) sm[j] = 0.f;
        for (int i = 0; i < NL; ++i) {
            #pragma unroll
            for (int j = 0; j < 4; ++j) {
                float a = acc[i][j] + partial[i * 4 + j][tq];
                w[i][j] = exp2_fast(-K2 * a);      // exp(score), no max-sub
                sm[j] += w[i][j];
            }
        }
        #pragma unroll
        for (int off = 32; off > 0; off >>= 1)
            for (int j = 0; j < 4; ++j) sm[j] += __shfl_xor(sm[j], off, 64);
        if ((t & 63) == 0) {
            for (int j = 0; j < 4; ++j) scrs[wave][j] = sm[j];
        }
        for (int i = 0; i < NL; ++i)
            *(v4*)&wbuf[NL * tq + i][0] = (v4){w[i][0], w[i][1], w[i][2], w[i][3]};
    }
    __syncthreads();
    if (t < 4)
        rzl[t] = __builtin_amdgcn_rcpf(scrs[0][t] + scrs[1][t] + scrs[2][t] + scrs[3][t]);
    __syncthreads();

    // ---- ctx: 4 h-groups of 128, each covers N/4 rows ----
    {
        int h = t & 127;
        int g = t >> 7;                 // 0..3
        int CH = N >> 2;                // 256 (s) or 128 (e)
        const float* Xb = X + (size_t)(g * CH) * H + h;
        const float* wb = &wbuf[g * CH][0];
        float c[4] = {0.f, 0.f, 0.f, 0.f};
        #pragma unroll 8
        for (int nn = 0; nn < CH; ++nn) {
            float x = Xb[(size_t)nn * H];
            float4 w4 = *(const float4*)(wb + nn * 4);   // broadcast b128
            c[0] += w4.x * x; c[1] += w4.y * x;
            c[2] += w4.z * x; c[3] += w4.w * x;
        }
        #pragma unroll
        for (int mj = 0; mj < 4; ++mj) part[g][mj][h] = c[mj];
    }
    __syncthreads();
    {
        int mj = t >> 7, h = t & 127;
        float s = part[0][mj][h] + part[1][mj][h] + part[2][mj][h] + part[3][mj][h];
        ctxout[(size_t)(m0 + mj) * H + h] = s * rzl[mj];
    }
}

// ---- final MLP + coherence: 8 m's/block, 2 m's/thread ----------------------
__global__ __launch_bounds__(512) void k_mlp(const float* __restrict__ attender,
                                             const float* __restrict__ ctx_s,
                                             const float* __restrict__ ctx_e,
                                             const float* __restrict__ WT_lin,
                                             const float* __restrict__ b_lin,
                                             const float* __restrict__ W_coh,
                                             const float* __restrict__ b_coh,
                                             float* __restrict__ out) {
    __shared__ float feats[8][3 * H];   // 12 KB
    __shared__ float red8[8][2];
    int m0 = blockIdx.x * 8;
    int t  = threadIdx.x;

    for (int i = t; i < 8 * 3 * H; i += 512) {
        int r = i / (3 * H), c = i % (3 * H);
        float v;
        if (c < H)            v = attender[(size_t)(m0 + r) * H + c];
        else if (c < 2 * H)   v = ctx_s[(size_t)(m0 + r) * H + (c - H)];
        else                  v = ctx_e[(size_t)(m0 + r) * H + (c - 2 * H)];
        feats[r][c] = v;
    }
    __syncthreads();

    int a   = t & 127;
    int jm  = t >> 7;                   // 0..3 -> m's jm and jm+4
    float acc0 = b_lin[a], acc1 = b_lin[a];
    #pragma unroll 8
    for (int k = 0; k < 3 * H; ++k) {
        float wv = WT_lin[k * H + a];   // shared stream: 2 fma per load
        acc0 += feats[jm][k] * wv;
        acc1 += feats[jm + 4][k] * wv;
    }
    float wc = W_coh[a];
    float v0 = fast_tanh(acc0) * wc;
    float v1 = fast_tanh(acc1) * wc;
    #pragma unroll
    for (int off = 32; off > 0; off >>= 1) {
        v0 += __shfl_down(v0, off, 64);
        v1 += __shfl_down(v1, off, 64);
    }
    if ((t & 63) == 0) { red8[t >> 6][0] = v0; red8[t >> 6][1] = v1; }
    __syncthreads();
    if (t < 4)      out[m0 + t]     = red8[2 * t][0] + red8[2 * t + 1][0] + b_coh[0];
    else if (t < 8) { int j = t - 4;  out[m0 + 4 + j] = red8[2 * j][1] + red8[2 * j + 1][1] + b_coh[0]; }
}

extern "C" void kernel_launch(void* const* d_in, const int* in_sizes, int n_in,
                              void* d_out, int out_size, void* d_ws, size_t ws_size,
                              hipStream_t stream) {
    const float* stmts    = (const float*)d_in[0];
    const float* eres     = (const float*)d_in[1];
    const float* attender = (const float*)d_in[2];
    const float* Wc_s     = (const float*)d_in[3];
    const float* bc_s     = (const float*)d_in[4];
    const float* ws_s     = (const float*)d_in[5];
    const float* Wc_e     = (const float*)d_in[7];
    const float* bc_e     = (const float*)d_in[8];
    const float* ws_e     = (const float*)d_in[9];
    const float* W_lin    = (const float*)d_in[11];
    const float* b_lin    = (const float*)d_in[12];
    const float* W_coh    = (const float*)d_in[13];
    const float* b_coh    = (const float*)d_in[14];
    float* out = (float*)d_out;

    float* ws    = (float*)d_ws;
    float* WT_s1 = ws;
    float* WT_s2 = WT_s1 + H * H;
    float* WT_e1 = WT_s2 + H * H;
    float* WT_e2 = WT_e1 + H * H;
    float* WT_li = WT_e2 + H * H;             // 384*128
    float* EAT_s = WT_li + 3 * H * H;         // [H][NS]
    float* EB_s  = EAT_s + NS * H;
    float* EAT_e = EB_s + M * H;              // [H][NE]
    float* EB_e  = EAT_e + NE * H;
    float* c_s   = EB_e + M * H;              // ctx_s [M][H]
    float* c_e   = c_s + (size_t)M * H;       // ctx_e [M][H]

    k_tr<<<448, 256, 0, stream>>>(Wc_s, Wc_e, W_lin, WT_s1, WT_s2, WT_e1, WT_e2, WT_li);
    k_proj<<<224, 256, 0, stream>>>(stmts, eres, attender, WT_s1, WT_s2, WT_e1, WT_e2,
                                    bc_s, bc_e, EAT_s, EB_s, EAT_e, EB_e);
    k_score_ctx<<<512, 512, 0, stream>>>(EAT_s, EB_s, ws_s, EAT_e, EB_e, ws_e,
                                         stmts, eres, c_s, c_e);
    k_mlp<<<M / 8, 512, 0, stream>>>(attender, c_s, c_e, WT_li, b_lin, W_coh, b_coh, out);
}

// Round 21
// 64.174 us; speedup vs baseline: 1.2437x; 1.2437x over previous
//
#include <hip/hip_runtime.h>
#include <math.h>

#define H   128
#define NS  1024
#define NE  512
#define M   1024
#define K2  2.8853900817779268f   // 2*log2(e)

typedef float v4 __attribute__((ext_vector_type(4)));
typedef float v2 __attribute__((ext_vector_type(2)));

__device__ __forceinline__ float exp2_fast(float x) {
#if __has_builtin(__builtin_amdgcn_exp2f)
    return __builtin_amdgcn_exp2f(x);
#else
    return __expf(x * 0.6931471805599453f);
#endif
}

__device__ __forceinline__ float fast_tanh(float x) {
    float e = __expf(2.0f * x);
    float r = __builtin_amdgcn_rcpf(1.0f + e);
    return 1.0f - 2.0f * r;
}

// ---- transpose (+K2 scale) the weight matrices ---------------------------
__global__ __launch_bounds__(256) void k_tr(const float* __restrict__ Wc_s,
                                            const float* __restrict__ Wc_e,
                                            const float* __restrict__ W_lin,
                                            float* __restrict__ WT_s1, float* __restrict__ WT_s2,
                                            float* __restrict__ WT_e1, float* __restrict__ WT_e2,
                                            float* __restrict__ WT_lin) {
    int idx = blockIdx.x * 256 + threadIdx.x;
    if (idx < 65536) {
        int t = idx >> 14, r = idx & 16383, k = r >> 7, hh = r & 127;
        const float* src = (t < 2) ? Wc_s : Wc_e;
        int off = (t & 1) * H;
        float v = K2 * src[hh * 256 + off + k];
        float* dst = (t == 0) ? WT_s1 : (t == 1) ? WT_s2 : (t == 2) ? WT_e1 : WT_e2;
        dst[r] = v;
    } else {
        int j2 = idx - 65536;             // [0, 49152)
        int k = j2 >> 7, a = j2 & 127;
        WT_lin[j2] = W_lin[a * 384 + k];
    }
}

// ---- projections -> exp2 domain ------------------------------------------
__global__ __launch_bounds__(256) void k_proj(const float* __restrict__ stmts,
                                              const float* __restrict__ eres,
                                              const float* __restrict__ attender,
                                              const float* __restrict__ WT_s1,
                                              const float* __restrict__ WT_s2,
                                              const float* __restrict__ WT_e1,
                                              const float* __restrict__ WT_e2,
                                              const float* __restrict__ bc_s,
                                              const float* __restrict__ bc_e,
                                              float* __restrict__ EAT_s, float* __restrict__ EB_s,
                                              float* __restrict__ EAT_e, float* __restrict__ EB_e) {
    __shared__ float xr[16][H];
    __shared__ float red[16][H];
    int b   = blockIdx.x;
    int tid = threadIdx.x;
    int t    = tid & 127;
    int half = tid >> 7;

    if (b < 96) {
        const float *X, *WT, *bias; float* OT; int r0, N;
        if (b < 64) { X = stmts; WT = WT_s1; bias = bc_s; OT = EAT_s; r0 = b * 16;        N = NS; }
        else        { X = eres;  WT = WT_e1; bias = bc_e; OT = EAT_e; r0 = (b - 64) * 16; N = NE; }
        for (int i = tid; i < 16 * H; i += 256) xr[i >> 7][i & 127] = X[(r0 + (i >> 7)) * H + (i & 127)];
        __syncthreads();
        float b0 = (half == 0) ? K2 * bias[t] : 0.0f;
        float acc[16];
        #pragma unroll
        for (int r = 0; r < 16; ++r) acc[r] = b0;
        int k0 = half * 64;
        #pragma unroll 4
        for (int k = k0; k < k0 + 64; ++k) {
            float wv = WT[k * H + t];
            #pragma unroll
            for (int r = 0; r < 16; ++r) acc[r] += xr[r][k] * wv;
        }
        if (half) {
            #pragma unroll
            for (int r = 0; r < 16; ++r) red[r][t] = acc[r];
        }
        __syncthreads();
        if (!half) {
            #pragma unroll
            for (int r = 0; r < 16; ++r) xr[r][t] = exp2_fast(acc[r] + red[r][t]);
        }
        __syncthreads();
        {
            int hh  = tid >> 1;
            int seg = (tid & 1) * 8;
            float4 v0 = make_float4(xr[seg + 0][hh], xr[seg + 1][hh], xr[seg + 2][hh], xr[seg + 3][hh]);
            float4 v1 = make_float4(xr[seg + 4][hh], xr[seg + 5][hh], xr[seg + 6][hh], xr[seg + 7][hh]);
            *(float4*)(OT + (size_t)hh * N + r0 + seg)     = v0;
            *(float4*)(OT + (size_t)hh * N + r0 + seg + 4) = v1;
        }
    } else {
        int b2 = b - 96;
        const float* WT = (b2 < 256) ? WT_s2 : WT_e2;
        float* O        = (b2 < 256) ? EB_s : EB_e;
        int r0          = (b2 & 255) * 4;
        float* xf = &xr[0][0];
        xf[tid]       = attender[r0 * H + tid];
        xf[tid + 256] = attender[r0 * H + 256 + tid];
        __syncthreads();
        float acc[4] = {0.f, 0.f, 0.f, 0.f};
        int k0 = half * 64;
        #pragma unroll 8
        for (int k = k0; k < k0 + 64; ++k) {
            float wv = WT[k * H + t];
            #pragma unroll
            for (int r = 0; r < 4; ++r) acc[r] += xf[r * H + k] * wv;
        }
        if (half) {
            #pragma unroll
            for (int r = 0; r < 4; ++r) red[r][t] = acc[r];
        }
        __syncthreads();
        if (!half) {
            #pragma unroll
            for (int r = 0; r < 4; ++r) O[(r0 + r) * H + t] = exp2_fast(acc[r] + red[r][t]);
        }
    }
}

// ---- fused score + softmax + context --------------------------------------
// score = -2 * sum_h ws[h]/(1+Ea*Eb)  (const dropped).  No max-subtraction:
// |score| <= 2*sum|ws| ~ 18, exp fits fp32 easily.  w = exp2(-K2*acc).
// QUAD: one rcp per 4 h's:  sum w_i/q_i = (n01*d23 + n23*d01)/(d01*d23).
#define QUAD(a0,a1,a2,a3, b0,b1,b2,b3, w0,w1,w2,w3, accv)              \
    { float q0 = fmaf(a0, b0, 1.0f), q1 = fmaf(a1, b1, 1.0f);          \
      float q2 = fmaf(a2, b2, 1.0f), q3 = fmaf(a3, b3, 1.0f);          \
      float d01 = q0 * q1, d23 = q2 * q3;                              \
      float n01 = w0 * q1; n01 = fmaf(w1, q0, n01);                    \
      float n23 = w2 * q3; n23 = fmaf(w3, q2, n23);                    \
      float nn = n01 * d23; nn = fmaf(n23, d01, nn);                   \
      float rr = __builtin_amdgcn_rcpf(d01 * d23);                     \
      accv = fmaf(nn, rr, accv); }

__global__ __launch_bounds__(512, 4) void k_score_ctx(const float* __restrict__ EAT_s,
                                                      const float* __restrict__ EB_s,
                                                      const float* __restrict__ ws_s,
                                                      const float* __restrict__ EAT_e,
                                                      const float* __restrict__ EB_e,
                                                      const float* __restrict__ ws_e,
                                                      const float* __restrict__ stmts,
                                                      const float* __restrict__ eres,
                                                      float* __restrict__ ctx_s,
                                                      float* __restrict__ ctx_e) {
    __shared__ float partial[16][257];  // h-half combine buffer
    __shared__ float wbuf[1024][4];     // w values (e-blocks: rows 0..511)
    __shared__ float part[4][4][H];     // ctx partials
    __shared__ float scrs[4][4], rzl[4];

    int b = blockIdx.x;                 // 0..511
    bool is_e = (b >= 256);
    int m0 = (is_e ? (b - 256) : b) * 4;
    const float* EAT = is_e ? EAT_e : EAT_s;
    const float* EB  = is_e ? EB_e  : EB_s;
    const float* wsv = is_e ? ws_e  : ws_s;
    const float* X   = is_e ? eres  : stmts;
    float* ctxout    = is_e ? ctx_e : ctx_s;
    int N  = is_e ? NE : NS;
    int NL = is_e ? 2 : 4;              // n's per thread
    int t  = threadIdx.x;
    int tq = t & 255;
    int hg = t >> 8;                    // 0/1: h-half
    int hbase = hg * 64;

    float acc[4][4] = {{0.f,0.f,0.f,0.f},{0.f,0.f,0.f,0.f},
                       {0.f,0.f,0.f,0.f},{0.f,0.f,0.f,0.f}};

    if (!is_e) {
        const float* base = EAT + 4 * tq;
        v4 a[4], an[4];
        #pragma unroll
        for (int k = 0; k < 4; ++k) a[k] = *(const v4*)(base + (size_t)(hbase + k) * NS);
        for (int ch = 0; ch < 16; ++ch) {
            int h0 = hbase + ch * 4;
            if (ch < 15) {
                #pragma unroll
                for (int k = 0; k < 4; ++k)
                    an[k] = *(const v4*)(base + (size_t)(h0 + 4 + k) * NS);
            }
            float wv[4];
            #pragma unroll
            for (int k = 0; k < 4; ++k) wv[k] = wsv[h0 + k];         // uniform
            #pragma unroll
            for (int mj = 0; mj < 4; ++mj) {
                float b0 = EB[(size_t)(m0 + mj) * H + h0 + 0];       // uniform
                float b1 = EB[(size_t)(m0 + mj) * H + h0 + 1];
                float b2 = EB[(size_t)(m0 + mj) * H + h0 + 2];
                float b3 = EB[(size_t)(m0 + mj) * H + h0 + 3];
                #pragma unroll
                for (int i = 0; i < 4; ++i)
                    QUAD(a[0][i], a[1][i], a[2][i], a[3][i],
                         b0, b1, b2, b3, wv[0], wv[1], wv[2], wv[3], acc[i][mj]);
            }
            #pragma unroll
            for (int k = 0; k < 4; ++k) a[k] = an[k];
        }
    } else {
        const float* base = EAT + 2 * tq;
        v2 a[4], an[4];
        #pragma unroll
        for (int k = 0; k < 4; ++k) a[k] = *(const v2*)(base + (size_t)(hbase + k) * NE);
        for (int ch = 0; ch < 16; ++ch) {
            int h0 = hbase + ch * 4;
            if (ch < 15) {
                #pragma unroll
                for (int k = 0; k < 4; ++k)
                    an[k] = *(const v2*)(base + (size_t)(h0 + 4 + k) * NE);
            }
            float wv[4];
            #pragma unroll
            for (int k = 0; k < 4; ++k) wv[k] = wsv[h0 + k];
            #pragma unroll
            for (int mj = 0; mj < 4; ++mj) {
                float b0 = EB[(size_t)(m0 + mj) * H + h0 + 0];
                float b1 = EB[(size_t)(m0 + mj) * H + h0 + 1];
                float b2 = EB[(size_t)(m0 + mj) * H + h0 + 2];
                float b3 = EB[(size_t)(m0 + mj) * H + h0 + 3];
                #pragma unroll
                for (int i = 0; i < 2; ++i)
                    QUAD(a[0][i], a[1][i], a[2][i], a[3][i],
                         b0, b1, b2, b3, wv[0], wv[1], wv[2], wv[3], acc[i][mj]);
            }
            #pragma unroll
            for (int k = 0; k < 4; ++k) a[k] = an[k];
        }
    }

    // ---- combine h-halves (hg1 -> LDS, hg0 adds), then exp + sum ----
    if (hg) {
        for (int i = 0; i < NL; ++i)
            #pragma unroll
            for (int j = 0; j < 4; ++j) partial[i * 4 + j][tq] = acc[i][j];
    }
    __syncthreads();
    int wave = t >> 6;                  // hg0 threads: waves 0..3
    if (!hg) {
        float w[4][4], sm[4];
        #pragma unroll
        for (int j = 0; j < 4; ++j) sm[j] = 0.f;
        for (int i = 0; i < NL; ++i) {
            #pragma unroll
            for (int j = 0; j < 4; ++j) {
                float a = acc[i][j] + partial[i * 4 + j][tq];
                w[i][j] = exp2_fast(-K2 * a);      // exp(score), no max-sub
                sm[j] += w[i][j];
            }
        }
        #pragma unroll
        for (int off = 32; off > 0; off >>= 1)
            for (int j = 0; j < 4; ++j) sm[j] += __shfl_xor(sm[j], off, 64);
        if ((t & 63) == 0) {
            for (int j = 0; j < 4; ++j) scrs[wave][j] = sm[j];
        }
        for (int i = 0; i < NL; ++i)
            *(v4*)&wbuf[NL * tq + i][0] = (v4){w[i][0], w[i][1], w[i][2], w[i][3]};
    }
    __syncthreads();
    if (t < 4)
        rzl[t] = __builtin_amdgcn_rcpf(scrs[0][t] + scrs[1][t] + scrs[2][t] + scrs[3][t]);
    __syncthreads();

    // ---- ctx: 4 h-groups of 128, each covers N/4 rows ----
    {
        int h = t & 127;
        int g = t >> 7;                 // 0..3
        int CH = N >> 2;                // 256 (s) or 128 (e)
        const float* Xb = X + (size_t)(g * CH) * H + h;
        const float* wb = &wbuf[g * CH][0];
        float c[4] = {0.f, 0.f, 0.f, 0.f};
        #pragma unroll 8
        for (int nn = 0; nn < CH; ++nn) {
            float x = Xb[(size_t)nn * H];
            float4 w4 = *(const float4*)(wb + nn * 4);   // broadcast b128
            c[0] += w4.x * x; c[1] += w4.y * x;
            c[2] += w4.z * x; c[3] += w4.w * x;
        }
        #pragma unroll
        for (int mj = 0; mj < 4; ++mj) part[g][mj][h] = c[mj];
    }
    __syncthreads();
    {
        int mj = t >> 7, h = t & 127;
        float s = part[0][mj][h] + part[1][mj][h] + part[2][mj][h] + part[3][mj][h];
        ctxout[(size_t)(m0 + mj) * H + h] = s * rzl[mj];
    }
}

// ---- final MLP + coherence -------------------------------------------------
__global__ __launch_bounds__(512) void k_mlp(const float* __restrict__ attender,
                                             const float* __restrict__ ctx_s,
                                             const float* __restrict__ ctx_e,
                                             const float* __restrict__ WT_lin,
                                             const float* __restrict__ b_lin,
                                             const float* __restrict__ W_coh,
                                             const float* __restrict__ b_coh,
                                             float* __restrict__ out) {
    __shared__ float feats[4][3 * H];   // 6 KB
    __shared__ float red2[8];
    int m0 = blockIdx.x * 4;
    int t  = threadIdx.x;

    for (int i = t; i < 4 * 3 * H; i += 512) {
        int r = i / (3 * H), c = i % (3 * H);
        float v;
        if (c < H)            v = attender[(size_t)(m0 + r) * H + c];
        else if (c < 2 * H)   v = ctx_s[(size_t)(m0 + r) * H + (c - H)];
        else                  v = ctx_e[(size_t)(m0 + r) * H + (c - 2 * H)];
        feats[r][c] = v;
    }
    __syncthreads();

    int a  = t & 127;
    int jm = t >> 7;
    float acc = b_lin[a];
    #pragma unroll 8
    for (int k = 0; k < 3 * H; ++k)
        acc += feats[jm][k] * WT_lin[k * H + a];
    float v = fast_tanh(acc) * W_coh[a];
    #pragma unroll
    for (int off = 32; off > 0; off >>= 1) v += __shfl_down(v, off, 64);
    if ((t & 63) == 0) red2[t >> 6] = v;
    __syncthreads();
    if (t < 4) out[m0 + t] = red2[2 * t] + red2[2 * t + 1] + b_coh[0];
}

extern "C" void kernel_launch(void* const* d_in, const int* in_sizes, int n_in,
                              void* d_out, int out_size, void* d_ws, size_t ws_size,
                              hipStream_t stream) {
    const float* stmts    = (const float*)d_in[0];
    const float* eres     = (const float*)d_in[1];
    const float* attender = (const float*)d_in[2];
    const float* Wc_s     = (const float*)d_in[3];
    const float* bc_s     = (const float*)d_in[4];
    const float* ws_s     = (const float*)d_in[5];
    const float* Wc_e     = (const float*)d_in[7];
    const float* bc_e     = (const float*)d_in[8];
    const float* ws_e     = (const float*)d_in[9];
    const float* W_lin    = (const float*)d_in[11];
    const float* b_lin    = (const float*)d_in[12];
    const float* W_coh    = (const float*)d_in[13];
    const float* b_coh    = (const float*)d_in[14];
    float* out = (float*)d_out;

    float* ws    = (float*)d_ws;
    float* WT_s1 = ws;
    float* WT_s2 = WT_s1 + H * H;
    float* WT_e1 = WT_s2 + H * H;
    float* WT_e2 = WT_e1 + H * H;
    float* WT_li = WT_e2 + H * H;             // 384*128
    float* EAT_s = WT_li + 3 * H * H;         // [H][NS]
    float* EB_s  = EAT_s + NS * H;
    float* EAT_e = EB_s + M * H;              // [H][NE]
    float* EB_e  = EAT_e + NE * H;
    float* c_s   = EB_e + M * H;              // ctx_s [M][H]
    float* c_e   = c_s + (size_t)M * H;       // ctx_e [M][H]

    k_tr<<<448, 256, 0, stream>>>(Wc_s, Wc_e, W_lin, WT_s1, WT_s2, WT_e1, WT_e2, WT_li);
    k_proj<<<608, 256, 0, stream>>>(stmts, eres, attender, WT_s1, WT_s2, WT_e1, WT_e2,
                                    bc_s, bc_e, EAT_s, EB_s, EAT_e, EB_e);
    k_score_ctx<<<512, 512, 0, stream>>>(EAT_s, EB_s, ws_s, EAT_e, EB_e, ws_e,
                                         stmts, eres, c_s, c_e);
    k_mlp<<<M / 4, 512, 0, stream>>>(attender, c_s, c_e, WT_li, b_lin, W_coh, b_coh, out);
}